// Round 5
// baseline (71.250 us; speedup 1.0000x reference)
//
#include <hip/hip_runtime.h>

#define IHH 306
#define KW 7
#define OUTC 10
#define FH 300
#define NPIX (FH * FH)            // 90000
#define KK (KW * KW)              // 49
#define BLK 256
#define GRID 352                  // ceil(NPIX / BLK)
#define NROWS 21                  // 10 hit-abs, 10 miss-abs, 1 x-sum
#define OUT4 472500               // 1890000 / 4
#define POOLED_END 90000
#define HIT_END 990000
#define CHUNK4 1343               // ceil(OUT4 / GRID); 352*1343 >= OUT4

// ws layout:
//   byte 0     : partials[NROWS][GRID] floats (29568 B)
//   byte 32768 : barrier {cnt, flag} ints — zeroed via hipMemsetAsync each call

__device__ __forceinline__ void grid_barrier(int* cnt, int* flag) {
    __syncthreads();
    if (threadIdx.x == 0) {
        __threadfence();   // release: make this block's stores visible device-wide
        const int old = __hip_atomic_fetch_add(cnt, 1, __ATOMIC_ACQ_REL,
                                               __HIP_MEMORY_SCOPE_AGENT);
        if (old == GRID - 1) {
            __hip_atomic_store(flag, 1, __ATOMIC_RELEASE,
                               __HIP_MEMORY_SCOPE_AGENT);
        } else {
            while (__hip_atomic_load(flag, __ATOMIC_ACQUIRE,
                                     __HIP_MEMORY_SCOPE_AGENT) == 0) {
                __builtin_amdgcn_s_sleep(1);
            }
        }
        __threadfence();   // acquire side for subsequent normal loads
    }
    __syncthreads();
}

__global__ __launch_bounds__(BLK, 2) void k_fused(
    const float* __restrict__ x,
    const float* __restrict__ kh,
    const float* __restrict__ km,
    float* __restrict__ partials,   // [NROWS][GRID]
    int* __restrict__ bar,          // {cnt, flag}
    float4* __restrict__ out)
{
    // ---- Phase 1: per-block partial sums -------------------------------
    __shared__ float2 s_k[KK * OUTC];   // [tap][o] = (kh, km)
    for (int t = threadIdx.x; t < KK * OUTC; t += BLK) {
        const int tap = t / OUTC;
        const int o = t - tap * OUTC;
        s_k[t] = make_float2(kh[o * KK + tap], km[o * KK + tap]);
    }
    __syncthreads();

    float ah[OUTC], am[OUTC];
    float sx = 0.0f;
#pragma unroll
    for (int o = 0; o < OUTC; ++o) { ah[o] = 0.0f; am[o] = 0.0f; }

    const int p = blockIdx.x * BLK + threadIdx.x;
    if (p < NPIX) {
        const int i = p / FH;
        const int j = p - i * FH;
        const float* xr = x + i * IHH + j;
        for (int u = 0; u < KW; ++u) {
            for (int v = 0; v < KW; ++v) {
                const float xv = xr[u * IHH + v];
                sx += xv;
                const float2* wk = &s_k[(u * KW + v) * OUTC];
#pragma unroll
                for (int o = 0; o < OUTC; ++o) {
                    const float2 w = wk[o];
                    ah[o] += fabsf(xv - w.x);   // abs folds to src modifier
                    am[o] += fabsf(xv - w.y);
                }
            }
        }
    }

    const int lane = threadIdx.x & 63;
    const int wave = threadIdx.x >> 6;
    __shared__ float s_red[BLK / 64][NROWS];

    float vals[NROWS];
#pragma unroll
    for (int o = 0; o < OUTC; ++o) { vals[o] = ah[o]; vals[OUTC + o] = am[o]; }
    vals[2 * OUTC] = sx;

#pragma unroll
    for (int r = 0; r < NROWS; ++r) {
        float v = vals[r];
#pragma unroll
        for (int s = 32; s > 0; s >>= 1) v += __shfl_xor(v, s);
        if (lane == 0) s_red[wave][r] = v;
    }
    __syncthreads();
    if (threadIdx.x < NROWS) {
        const float s = s_red[0][threadIdx.x] + s_red[1][threadIdx.x]
                      + s_red[2][threadIdx.x] + s_red[3][threadIdx.x];
        partials[threadIdx.x * GRID + blockIdx.x] = s;
    }

    grid_barrier(&bar[0], &bar[1]);

    // ---- Phase 2: redundant per-block final reduce + fill --------------
    __shared__ float s_part[NROWS][8];
    __shared__ float s_ks[2 * OUTC];
    __shared__ float s_o[3][OUTC];
    const int t = threadIdx.x;

    if (t < NROWS * 8) {             // threads 0..167: table reduce
        const int r = t >> 3;
        const int s8 = t & 7;
        const float* row = partials + r * GRID;
        float acc = 0.0f;
        for (int c = s8; c < GRID; c += 8) acc += row[c];
        s_part[r][s8] = acc;
    } else if (t >= 192 && t < 192 + 2 * OUTC) {   // threads 192..211: ksums
        const int a = t - 192;
        const float* kp = (a < OUTC) ? (kh + a * KK) : (km + (a - OUTC) * KK);
        float s = 0.0f;
        for (int q = 0; q < KK; ++q) s += kp[q];
        s_ks[a] = s;
    }
    __syncthreads();
    if (t < NROWS) {
        float f = 0.0f;
#pragma unroll
        for (int s = 0; s < 8; ++s) f += s_part[t][s];
        s_part[t][0] = f;
    }
    __syncthreads();
    if (t < OUTC) {
        const float Sx = s_part[2 * OUTC][0];
        const float Ah = s_part[t][0];
        const float Am = s_part[OUTC + t][0];
        const float Fh = 0.5f * ((Sx - (float)NPIX * s_ks[t]) - Ah);
        const float Fm = 0.5f * ((Sx - (float)NPIX * s_ks[OUTC + t]) + Am);
        s_o[0][t] = Fh - Fm;        // pooled value
        s_o[1][t] = Fh;             // F_hit_list value
        s_o[2][t] = Fm;             // F_miss_list value
    }
    __syncthreads();

    const int start = blockIdx.x * CHUNK4;
    const int stop = min(start + CHUNK4, OUT4);
    for (int i4 = start + t; i4 < stop; i4 += BLK) {
        const int base = i4 * 4;
        float v;
        if (base < POOLED_END) {
            v = s_o[0][base / 9000];                    // pooled: 10 ch x 9000
        } else if (base < HIT_END) {
            v = s_o[1][(base - POOLED_END) / 90000];    // F_hit: 10 ch x 90000
        } else {
            v = s_o[2][(base - HIT_END) / 90000];       // F_miss: 10 ch x 90000
        }
        out[i4] = make_float4(v, v, v, v);
    }
}

extern "C" void kernel_launch(void* const* d_in, const int* in_sizes, int n_in,
                              void* d_out, int out_size, void* d_ws, size_t ws_size,
                              hipStream_t stream) {
    const float* x  = (const float*)d_in[0];
    const float* kh = (const float*)d_in[1];
    const float* km = (const float*)d_in[2];
    float4* out = (float4*)d_out;

    float* partials = (float*)d_ws;                      // NROWS*GRID floats
    int* bar = (int*)((char*)d_ws + 32768);              // {cnt, flag}

    (void)hipMemsetAsync(bar, 0, 128, stream);
    k_fused<<<GRID, BLK, 0, stream>>>(x, kh, km, partials, bar, out);
}

// Round 6
// 39.356 us; speedup vs baseline: 1.8104x; 1.8104x over previous
//
#include <hip/hip_runtime.h>

#define IHH 306
#define KW 7
#define OUTC 10
#define FH 300
#define NPIX (FH * FH)            // 90000
#define KK (KW * KW)              // 49
#define BLK 512
#define GRID 176                  // 1 block/CU, all co-resident
#define PPB 512                   // pixels per block
#define NROWS 21                  // 10 hit-abs, 10 miss-abs, 1 x-sum
#define OUT4 472500               // 1890000 / 4
#define POOLED_END 90000
#define HIT_END 990000
#define CHUNK4 2685               // ceil(OUT4 / GRID)

// ws layout:
//   0     : partials[NROWS][GRID] floats (14784 B)
//   16384 : done[GRID] flags, 64B stride (11264 B)   -- memset 0 each call
//   27648 : pub[30] floats                            -- memset 0 each call
//   27776 : ready flag (int)                          -- memset 0 each call

#define AL(p)    __hip_atomic_load((p), __ATOMIC_RELAXED, __HIP_MEMORY_SCOPE_AGENT)
#define AS(p, v) __hip_atomic_store((p), (v), __ATOMIC_RELAXED, __HIP_MEMORY_SCOPE_AGENT)

__global__ __launch_bounds__(BLK) void k_fused(
    const float* __restrict__ x,
    const float* __restrict__ kh,
    const float* __restrict__ km,
    float* __restrict__ partials,
    int* __restrict__ done,
    float* __restrict__ pub,
    int* __restrict__ ready,
    float4* __restrict__ out)
{
    __shared__ float2 s_k[KK * OUTC];   // [tap][o] = (kh, km)
    __shared__ float s_red[BLK / 64][NROWS];
    __shared__ float s_part[NROWS][16];
    __shared__ float s_ks[2 * OUTC];
    __shared__ float s_o[3 * OUTC];     // [0..9]=pooled, [10..19]=Fh, [20..29]=Fm

    const int t = threadIdx.x;
    const int b = blockIdx.x;

    // ---- Phase 1: per-block partial sums -------------------------------
    for (int i = t; i < KK * OUTC; i += BLK) {
        const int tap = i / OUTC;
        const int o = i - tap * OUTC;
        s_k[i] = make_float2(kh[o * KK + tap], km[o * KK + tap]);
    }
    __syncthreads();

    float ah[OUTC], am[OUTC];
    float sx = 0.0f;
#pragma unroll
    for (int o = 0; o < OUTC; ++o) { ah[o] = 0.0f; am[o] = 0.0f; }

    const int p = b * PPB + t;
    if (p < NPIX) {
        const int i = p / FH;
        const int j = p - i * FH;
        const float* xr = x + i * IHH + j;
        for (int u = 0; u < KW; ++u) {
            for (int v = 0; v < KW; ++v) {
                const float xv = xr[u * IHH + v];
                sx += xv;
                const float2* wk = &s_k[(u * KW + v) * OUTC];
#pragma unroll
                for (int o = 0; o < OUTC; ++o) {
                    const float2 w = wk[o];
                    ah[o] += fabsf(xv - w.x);
                    am[o] += fabsf(xv - w.y);
                }
            }
        }
    }

    const int lane = t & 63;
    const int wave = t >> 6;
    float vals[NROWS];
#pragma unroll
    for (int o = 0; o < OUTC; ++o) { vals[o] = ah[o]; vals[OUTC + o] = am[o]; }
    vals[2 * OUTC] = sx;
#pragma unroll
    for (int r = 0; r < NROWS; ++r) {
        float v = vals[r];
#pragma unroll
        for (int s = 32; s > 0; s >>= 1) v += __shfl_xor(v, s);
        if (lane == 0) s_red[wave][r] = v;
    }
    __syncthreads();
    if (t < NROWS) {
        float s = 0.0f;
#pragma unroll
        for (int w = 0; w < BLK / 64; ++w) s += s_red[w][t];
        AS(&partials[t * GRID + b], s);     // agent-visible store
    }
    __syncthreads();                        // drains vmcnt: stores complete
    if (t == 0) {
        __threadfence();
        __hip_atomic_store(&done[b * 16], 1, __ATOMIC_RELEASE,
                           __HIP_MEMORY_SCOPE_AGENT);
    }

    if (b == 0) {
        // ---- Block 0: gather, reduce, publish --------------------------
        if (t >= 336 && t < 336 + 2 * OUTC) {      // ksums during the wait
            const int a = t - 336;
            const float* kp = (a < OUTC) ? (kh + a * KK)
                                         : (km + (a - OUTC) * KK);
            float s = 0.0f;
            for (int q = 0; q < KK; ++q) s += kp[q];
            s_ks[a] = s;
        }
        if (t < GRID) {                             // one flag per thread
            while (AL(&done[t * 16]) == 0) __builtin_amdgcn_s_sleep(8);
        }
        __syncthreads();
        __threadfence();                            // acquire side

        if (t < NROWS * 16) {                       // 336 threads: table reduce
            const int r = t >> 4;
            const int s16 = t & 15;
            float acc = 0.0f;
            for (int c = s16; c < GRID; c += 16)
                acc += AL(&partials[r * GRID + c]);
            s_part[r][s16] = acc;
        }
        __syncthreads();
        if (t < NROWS) {
            float f = 0.0f;
#pragma unroll
            for (int s = 0; s < 16; ++s) f += s_part[t][s];
            s_part[t][0] = f;
        }
        __syncthreads();
        if (t < OUTC) {
            const float Sx = s_part[2 * OUTC][0];
            const float Ah = s_part[t][0];
            const float Am = s_part[OUTC + t][0];
            const float Fh = 0.5f * ((Sx - (float)NPIX * s_ks[t]) - Ah);
            const float Fm = 0.5f * ((Sx - (float)NPIX * s_ks[OUTC + t]) + Am);
            s_o[t] = Fh - Fm;
            s_o[OUTC + t] = Fh;
            s_o[2 * OUTC + t] = Fm;
            AS(&pub[t], Fh - Fm);
            AS(&pub[OUTC + t], Fh);
            AS(&pub[2 * OUTC + t], Fm);
        }
        __syncthreads();                            // drain publish stores
        if (t == 0) {
            __threadfence();
            __hip_atomic_store(ready, 1, __ATOMIC_RELEASE,
                               __HIP_MEMORY_SCOPE_AGENT);
        }
        __syncthreads();
    } else {
        // ---- Other blocks: wait for the 30 scalars ---------------------
        if (t == 0) {
            while (AL(ready) == 0) __builtin_amdgcn_s_sleep(16);
        }
        __syncthreads();
        if (t < 3 * OUTC) s_o[t] = AL(&pub[t]);
        __syncthreads();
    }

    // ---- Fill ----------------------------------------------------------
    const int start = b * CHUNK4;
    const int stop = min(start + CHUNK4, OUT4);
    for (int i4 = start + t; i4 < stop; i4 += BLK) {
        const int base = i4 * 4;
        float v;
        if (base < POOLED_END) {
            v = s_o[base / 9000];                         // pooled
        } else if (base < HIT_END) {
            v = s_o[OUTC + (base - POOLED_END) / 90000];  // F_hit
        } else {
            v = s_o[2 * OUTC + (base - HIT_END) / 90000]; // F_miss
        }
        out[i4] = make_float4(v, v, v, v);
    }
}

extern "C" void kernel_launch(void* const* d_in, const int* in_sizes, int n_in,
                              void* d_out, int out_size, void* d_ws, size_t ws_size,
                              hipStream_t stream) {
    const float* x  = (const float*)d_in[0];
    const float* kh = (const float*)d_in[1];
    const float* km = (const float*)d_in[2];
    float4* out = (float4*)d_out;

    float* partials = (float*)d_ws;                      // 14784 B
    int*   done     = (int*)((char*)d_ws + 16384);       // 176 x 64B
    float* pub      = (float*)((char*)d_ws + 27648);     // 30 floats
    int*   ready    = (int*)((char*)d_ws + 27776);

    (void)hipMemsetAsync((char*)d_ws + 16384, 0, 12288, stream);
    k_fused<<<GRID, BLK, 0, stream>>>(x, kh, km, partials, done, pub, ready, out);
}

// Round 7
// 33.759 us; speedup vs baseline: 2.1105x; 1.1658x over previous
//
#include <hip/hip_runtime.h>

#define IHH 306
#define KW 7
#define OUTC 10
#define FH 300
#define NPIX (FH * FH)            // 90000
#define KK (KW * KW)              // 49
#define BLK 512
#define GRID 176                  // <= 1 block/CU, all co-resident
#define PPB 512                   // pixels per block
#define NROWS 21                  // 10 hit-abs, 10 miss-abs, 1 x-sum
#define OUT4 472500               // 1890000 / 4
#define POOLED_END 90000
#define HIT_END 990000
#define CHUNK4 2685               // ceil(OUT4 / GRID)

// ws layout:
//   0     : partials[NROWS][GRID] floats (14784 B)
//   16384 : done[GRID] flags, 64B stride (11264 B)   -- memset 0 each call
//   27648 : pub[30] floats
//   27776 : ready flag (int)                          -- memset 0 each call
//
// Cross-block protocol (fence-free): every datum that crosses a block
// boundary is written/read with agent-scope RELAXED atomics (they bypass
// the non-coherent L1/L2 to the coherence point). Ordering comes from the
// vmcnt(0) drain the compiler emits before every s_barrier: a flag store
// issued after __syncthreads() cannot precede the data stores before it.
// No __threadfence => no buffer_wbl2/buffer_inv cache-maintenance storm.

#define AL(p)    __hip_atomic_load((p), __ATOMIC_RELAXED, __HIP_MEMORY_SCOPE_AGENT)
#define AS(p, v) __hip_atomic_store((p), (v), __ATOMIC_RELAXED, __HIP_MEMORY_SCOPE_AGENT)

__global__ __launch_bounds__(BLK) void k_fused(
    const float* __restrict__ x,
    const float* __restrict__ kh,
    const float* __restrict__ km,
    float* __restrict__ partials,
    int* __restrict__ done,
    float* __restrict__ pub,
    int* __restrict__ ready,
    float4* __restrict__ out)
{
    __shared__ float2 s_k[KK * OUTC];   // [tap][o] = (kh, km)
    __shared__ float s_red[BLK / 64][NROWS];
    __shared__ float s_part[NROWS][16];
    __shared__ float s_ks[2 * OUTC];
    __shared__ float s_o[3 * OUTC];     // [0..9]=pooled, [10..19]=Fh, [20..29]=Fm

    const int t = threadIdx.x;
    const int b = blockIdx.x;

    // ---- Phase 1: per-block partial sums -------------------------------
    for (int i = t; i < KK * OUTC; i += BLK) {
        const int tap = i / OUTC;
        const int o = i - tap * OUTC;
        s_k[i] = make_float2(kh[o * KK + tap], km[o * KK + tap]);
    }
    __syncthreads();

    float ah[OUTC], am[OUTC];
    float sx = 0.0f;
#pragma unroll
    for (int o = 0; o < OUTC; ++o) { ah[o] = 0.0f; am[o] = 0.0f; }

    const int p = b * PPB + t;
    if (p < NPIX) {
        const int i = p / FH;
        const int j = p - i * FH;
        const float* xr = x + i * IHH + j;
        for (int u = 0; u < KW; ++u) {
            for (int v = 0; v < KW; ++v) {
                const float xv = xr[u * IHH + v];
                sx += xv;
                const float2* wk = &s_k[(u * KW + v) * OUTC];
#pragma unroll
                for (int o = 0; o < OUTC; ++o) {
                    const float2 w = wk[o];
                    ah[o] += fabsf(xv - w.x);
                    am[o] += fabsf(xv - w.y);
                }
            }
        }
    }

    const int lane = t & 63;
    const int wave = t >> 6;
    float vals[NROWS];
#pragma unroll
    for (int o = 0; o < OUTC; ++o) { vals[o] = ah[o]; vals[OUTC + o] = am[o]; }
    vals[2 * OUTC] = sx;
#pragma unroll
    for (int r = 0; r < NROWS; ++r) {
        float v = vals[r];
#pragma unroll
        for (int s = 32; s > 0; s >>= 1) v += __shfl_xor(v, s);
        if (lane == 0) s_red[wave][r] = v;
    }
    __syncthreads();
    if (t < NROWS) {
        float s = 0.0f;
#pragma unroll
        for (int w = 0; w < BLK / 64; ++w) s += s_red[w][t];
        AS(&partials[t * GRID + b], s);     // coherence-point store
    }
    __syncthreads();                        // implies s_waitcnt vmcnt(0): stores done
    if (t == 0) AS(&done[b * 16], 1);       // flag cannot precede data

    if (b == 0) {
        // ---- Block 0: gather, reduce, publish --------------------------
        if (t >= 336 && t < 336 + 2 * OUTC) {      // ksums during the wait
            const int a = t - 336;
            const float* kp = (a < OUTC) ? (kh + a * KK)
                                         : (km + (a - OUTC) * KK);
            float s = 0.0f;
            for (int q = 0; q < KK; ++q) s += kp[q];
            s_ks[a] = s;
        }
        if (t < GRID) {                             // one flag per thread
            while (AL(&done[t * 16]) == 0) __builtin_amdgcn_s_sleep(2);
        }
        __syncthreads();

        if (t < NROWS * 16) {                       // 336 threads: table reduce
            const int r = t >> 4;
            const int s16 = t & 15;
            float acc = 0.0f;
            for (int c = s16; c < GRID; c += 16)
                acc += AL(&partials[r * GRID + c]);
            s_part[r][s16] = acc;
        }
        __syncthreads();
        if (t < NROWS) {
            float f = 0.0f;
#pragma unroll
            for (int s = 0; s < 16; ++s) f += s_part[t][s];
            s_part[t][0] = f;
        }
        __syncthreads();
        if (t < OUTC) {
            const float Sx = s_part[2 * OUTC][0];
            const float Ah = s_part[t][0];
            const float Am = s_part[OUTC + t][0];
            const float Fh = 0.5f * ((Sx - (float)NPIX * s_ks[t]) - Ah);
            const float Fm = 0.5f * ((Sx - (float)NPIX * s_ks[OUTC + t]) + Am);
            s_o[t] = Fh - Fm;
            s_o[OUTC + t] = Fh;
            s_o[2 * OUTC + t] = Fm;
            AS(&pub[t], Fh - Fm);
            AS(&pub[OUTC + t], Fh);
            AS(&pub[2 * OUTC + t], Fm);
        }
        __syncthreads();                            // vmcnt(0): pub stores done
        if (t == 0) AS(ready, 1);
        __syncthreads();
    } else {
        // ---- Other blocks: wait for the 30 scalars ---------------------
        if (t == 0) {
            while (AL(ready) == 0) __builtin_amdgcn_s_sleep(8);
        }
        __syncthreads();
        if (t < 3 * OUTC) s_o[t] = AL(&pub[t]);
        __syncthreads();
    }

    // ---- Fill ----------------------------------------------------------
    const int start = b * CHUNK4;
    const int stop = min(start + CHUNK4, OUT4);
    for (int i4 = start + t; i4 < stop; i4 += BLK) {
        const int base = i4 * 4;
        float v;
        if (base < POOLED_END) {
            v = s_o[base / 9000];                         // pooled
        } else if (base < HIT_END) {
            v = s_o[OUTC + (base - POOLED_END) / 90000];  // F_hit
        } else {
            v = s_o[2 * OUTC + (base - HIT_END) / 90000]; // F_miss
        }
        out[i4] = make_float4(v, v, v, v);
    }
}

extern "C" void kernel_launch(void* const* d_in, const int* in_sizes, int n_in,
                              void* d_out, int out_size, void* d_ws, size_t ws_size,
                              hipStream_t stream) {
    const float* x  = (const float*)d_in[0];
    const float* kh = (const float*)d_in[1];
    const float* km = (const float*)d_in[2];
    float4* out = (float4*)d_out;

    float* partials = (float*)d_ws;                      // 14784 B
    int*   done     = (int*)((char*)d_ws + 16384);       // 176 x 64B
    float* pub      = (float*)((char*)d_ws + 27648);     // 30 floats
    int*   ready    = (int*)((char*)d_ws + 27776);

    (void)hipMemsetAsync((char*)d_ws + 16384, 0, 12288, stream);
    k_fused<<<GRID, BLK, 0, stream>>>(x, kh, km, partials, done, pub, ready, out);
}